// Round 1
// baseline (38367.859 us; speedup 1.0000x reference)
//
#include <hip/hip_runtime.h>
#include <hip/hip_cooperative_groups.h>
#include <math.h>

namespace cg = cooperative_groups;

#define BB 64
#define TT 512
#define EE 512
#define UU 1024
#define GG 4096
#define K1 1024
#define K2 2048

// workspace layout (float offsets)
#define OFF_TZ 0u
#define SZ_TZ  (1024u*4096u)            // tz[v][u][4 gates]
#define OFF_P0 (OFF_TZ + SZ_TZ)
#define SZ_P0  (256u*1024u*16u)         // P0[wg][k][j*4+g]
#define OFF_P1 (OFF_P0 + SZ_P0)
#define SZ_P1  (256u*2048u*16u)         // P1[wg][k][j*4+g]
#define OFF_H0 (OFF_P1 + SZ_P1)
#define SZ_H0  (2u*1024u*64u)           // h0T[parity][u][b]
#define OFF_H1 (OFF_H0 + SZ_H0)
#define SZ_H1  (3u*1024u*64u)           // h1T[slot][u][b]

// ---------------- pack kernels ----------------
__global__ __launch_bounds__(256) void pack_p0_k(const float* __restrict__ U0,
                                                 float* __restrict__ P0) {
  unsigned t = blockIdx.x * 256u + threadIdx.x;        // < 1024*4096
  unsigned k = t >> 12, col = t & 4095u;
  unsigned g = col >> 10, u = col & 1023u;
  unsigned w = u >> 2, j = u & 3u;
  P0[((w << 10) + k) * 16u + (j << 2) + g] = U0[t];
}

__global__ __launch_bounds__(256) void pack_p1_k(const float* __restrict__ W1,
                                                 const float* __restrict__ U1,
                                                 float* __restrict__ P1) {
  unsigned t = blockIdx.x * 256u + threadIdx.x;        // < 2048*4096
  unsigned k = t >> 12, col = t & 4095u;
  float v = (k < 1024u) ? W1[(k << 12) + col] : U1[((k - 1024u) << 12) + col];
  unsigned g = col >> 10, u = col & 1023u;
  unsigned w = u >> 2, j = u & 3u;
  P1[((w << 11) + k) * 16u + (j << 2) + g] = v;
}

// ---------------- tz = embed @ W0 + b0, stored [v][u][g] ----------------
__global__ __launch_bounds__(256) void tz_gemm_k(const float* __restrict__ embed,
                                                 const float* __restrict__ W0,
                                                 const float* __restrict__ b0,
                                                 float* __restrict__ tz) {
  const int c0 = blockIdx.x << 6;    // col tile (64 wide), within one gate block
  const int v0 = blockIdx.y << 6;    // vocab tile
  __shared__ float As[32][65];
  __shared__ float Bs[32][65];
  const int tid = threadIdx.x;
  const int tr = tid >> 4, tc = tid & 15;
  float acc[4][4];
#pragma unroll
  for (int r = 0; r < 4; ++r)
#pragma unroll
    for (int c = 0; c < 4; ++c) acc[r][c] = 0.f;

  for (int kc = 0; kc < EE; kc += 32) {
    __syncthreads();
    {
      int kk = tid & 31, vv = tid >> 5;
#pragma unroll
      for (int p = 0; p < 8; ++p)
        As[kk][vv + (p << 3)] = embed[(size_t)(v0 + vv + (p << 3)) * EE + kc + kk];
    }
    {
      int cc = tid & 63, kk = tid >> 6;
#pragma unroll
      for (int p = 0; p < 8; ++p)
        Bs[kk + (p << 2)][cc] = W0[(size_t)(kc + kk + (p << 2)) * GG + c0 + cc];
    }
    __syncthreads();
#pragma unroll 8
    for (int kk = 0; kk < 32; ++kk) {
      float av[4], bv[4];
#pragma unroll
      for (int r = 0; r < 4; ++r) av[r] = As[kk][(tr << 2) + r];
#pragma unroll
      for (int c = 0; c < 4; ++c) bv[c] = Bs[kk][(tc << 2) + c];
#pragma unroll
      for (int r = 0; r < 4; ++r)
#pragma unroll
        for (int c = 0; c < 4; ++c) acc[r][c] = fmaf(av[r], bv[c], acc[r][c]);
    }
  }
#pragma unroll
  for (int r = 0; r < 4; ++r) {
    int v = v0 + (tr << 2) + r;
#pragma unroll
    for (int c = 0; c < 4; ++c) {
      int col = c0 + (tc << 2) + c;
      int g = col >> 10, u = col & 1023;
      tz[(size_t)v * 4096 + (u << 2) + g] = acc[r][c] + b0[col];
    }
  }
}

// ---------------- persistent cooperative LSTM ----------------
// grid 256 x 512 threads. WG wg owns units [wg*4, wg*4+4). Waves split K.
// Activations transposed: hT[u][b]. c-state in registers of threads tid<256.
__global__ __launch_bounds__(512) void lstm_coop_k(const int* __restrict__ tokens,
                                                   const float* __restrict__ tz,
                                                   const float* __restrict__ P0,
                                                   const float* __restrict__ P1,
                                                   const float* __restrict__ b1,
                                                   float* __restrict__ h0T,
                                                   float* __restrict__ h1T,
                                                   float* __restrict__ out) {
  cg::grid_group grid = cg::this_grid();
  const int tid = threadIdx.x;
  const int wg = blockIdx.x;                 // 0..255
  const int lane = tid & 63;                 // = batch row b
  const int wave = tid >> 6;                 // 0..7
  const int wv = __builtin_amdgcn_readfirstlane(wave);
  const int ubase = wg << 2;
  const int j = tid >> 6;                    // unit offset for update threads (tid<256)

  __shared__ float zp[512 * 17];

  const float* __restrict__ P0w = P0 + (size_t)wg * (K1 * 16);
  const float* __restrict__ P1w = P1 + (size_t)wg * (K2 * 16);

  float c0 = 0.f, c1 = 0.f;
  float b1v[4] = {0.f, 0.f, 0.f, 0.f};
  if (tid < 256) {
#pragma unroll
    for (int g = 0; g < 4; ++g) b1v[g] = b1[(g << 10) + ubase + j];
  }

  for (int ss = 0; ss <= TT; ++ss) {
    const int wp = ss & 1, rp = wp ^ 1;
    const int s1w = (ss + 2) % 3;            // slot for h1(ss-1)
    const int s1r = (ss + 1) % 3;            // slot of h1(ss-2)

    // ---- phase A: layer 0, computing h0(ss) ----
    if (ss < TT) {
      float4 tzv = make_float4(0.f, 0.f, 0.f, 0.f);
      if (tid < 256) {
        int tok = tokens[lane * TT + ss];
        tzv = ((const float4*)tz)[(size_t)tok * 1024 + ubase + j];
      }
      float acc[16];
#pragma unroll
      for (int q = 0; q < 16; ++q) acc[q] = 0.f;
      {
        const int k0 = wv << 7;              // 128 k's per wave
        const float* __restrict__ aa = h0T + rp * (UU * BB) + k0 * BB + lane;
        const float* __restrict__ wwb = P0w + (size_t)k0 * 16;
#pragma unroll 4
        for (int kk = 0; kk < 128; ++kk) {
          float a = aa[kk * BB];
          const float* __restrict__ ww = wwb + kk * 16;
#pragma unroll
          for (int q = 0; q < 16; ++q) acc[q] = fmaf(a, ww[q], acc[q]);
        }
      }
#pragma unroll
      for (int q = 0; q < 16; ++q) zp[tid * 17 + q] = acc[q];
      __syncthreads();
      if (tid < 256) {
        float z[4];
#pragma unroll
        for (int g = 0; g < 4; ++g) {
          float s = ((const float*)&tzv)[g];
#pragma unroll
          for (int w8 = 0; w8 < 8; ++w8) s += zp[(w8 * 64 + lane) * 17 + (j << 2) + g];
          z[g] = s;
        }
        float iG = 1.f / (1.f + expf(-z[0]));
        float fG = 1.f / (1.f + expf(-z[1]));
        float gG = tanhf(z[2]);
        float oG = 1.f / (1.f + expf(-z[3]));
        c0 = fG * c0 + iG * gG;
        float h = oG * tanhf(c0);
        h0T[wp * (UU * BB) + (ubase + j) * BB + lane] = h;
      }
    }

    // ---- phase B: layer 1, computing h1(ss-1) (skewed; independent of phase A) ----
    if (ss >= 1) {
      __syncthreads();                       // zp reuse guard
      float acc[16];
#pragma unroll
      for (int q = 0; q < 16; ++q) acc[q] = 0.f;
      {
        const int k0 = wv << 8;              // 256 k's per wave
        const float* __restrict__ aa = (wv < 4)
            ? (h0T + rp * (UU * BB) + k0 * BB + lane)                // W1 part: h0(ss-1)
            : (h1T + s1r * (UU * BB) + (k0 - 1024) * BB + lane);     // U1 part: h1(ss-2)
        const float* __restrict__ wwb = P1w + (size_t)k0 * 16;
#pragma unroll 4
        for (int kk = 0; kk < 256; ++kk) {
          float a = aa[kk * BB];
          const float* __restrict__ ww = wwb + kk * 16;
#pragma unroll
          for (int q = 0; q < 16; ++q) acc[q] = fmaf(a, ww[q], acc[q]);
        }
      }
#pragma unroll
      for (int q = 0; q < 16; ++q) zp[tid * 17 + q] = acc[q];
      __syncthreads();
      if (tid < 256) {
        float z[4];
#pragma unroll
        for (int g = 0; g < 4; ++g) {
          float s = b1v[g];
#pragma unroll
          for (int w8 = 0; w8 < 8; ++w8) s += zp[(w8 * 64 + lane) * 17 + (j << 2) + g];
          z[g] = s;
        }
        float iG = 1.f / (1.f + expf(-z[0]));
        float fG = 1.f / (1.f + expf(-z[1]));
        float gG = tanhf(z[2]);
        float oG = 1.f / (1.f + expf(-z[3]));
        c1 = fG * c1 + iG * gG;
        float h = oG * tanhf(c1);
        h1T[s1w * (UU * BB) + (ubase + j) * BB + lane] = h;
        out[(size_t)lane * (TT * UU) + (size_t)(ss - 1) * UU + ubase + j] = h;
      }
    }
    grid.sync();
  }
}

// ---------------- host ----------------
extern "C" void kernel_launch(void* const* d_in, const int* in_sizes, int n_in,
                              void* d_out, int out_size, void* d_ws, size_t ws_size,
                              hipStream_t stream) {
  const int*   tokens = (const int*)d_in[0];
  const float* embed  = (const float*)d_in[1];
  const float* W0     = (const float*)d_in[2];
  const float* U0     = (const float*)d_in[3];
  const float* b0     = (const float*)d_in[4];
  const float* W1     = (const float*)d_in[5];
  const float* U1     = (const float*)d_in[6];
  const float* b1     = (const float*)d_in[7];
  float* ws  = (float*)d_ws;
  float* tz  = ws + OFF_TZ;
  float* P0  = ws + OFF_P0;
  float* P1  = ws + OFF_P1;
  float* h0T = ws + OFF_H0;
  float* h1T = ws + OFF_H1;
  float* out = (float*)d_out;

  // zero recurrent state buffers (ws is poisoned 0xAA before every call)
  hipMemsetAsync(h0T, 0, (SZ_H0 + SZ_H1) * sizeof(float), stream);

  pack_p0_k<<<16384, 256, 0, stream>>>(U0, P0);
  pack_p1_k<<<32768, 256, 0, stream>>>(W1, U1, P1);
  tz_gemm_k<<<dim3(64, 16), 256, 0, stream>>>(embed, W0, b0, tz);

  void* args[] = {(void*)&tokens, (void*)&tz, (void*)&P0, (void*)&P1,
                  (void*)&b1, (void*)&h0T, (void*)&h1T, (void*)&out};
  hipLaunchCooperativeKernel((void*)lstm_coop_k, dim3(256), dim3(512), args, 0, stream);
}